// Round 9
// baseline (94.073 us; speedup 1.0000x reference)
//
#include <hip/hip_runtime.h>
#include <math.h>

// ---------------------------------------------------------------------------
// InputEmbedder. Sizes: B=2, T=15000, CHNLS=21, HIDDEN=128, Tr=462
// R9: R7's register-G fused kernel, but WITHOUT the __launch_bounds__(512,4)
// VGPR cap (which forced 64 VGPRs and spilled G[32] to scratch -- the real
// cause of the R6/R7 regression; WRITE_SIZE 34-59MB vs 15MB output).
// conv_stack (T5=21) and transpose_prep unchanged from R8.
// ---------------------------------------------------------------------------

#define NB 2
#define TR 462
#define C5 2688          // HIDDEN*CHNLS
#define OUTROW 4096      // HIDDEN*32

// conv-stack tiling: 22 tiles of T5=21 stage-5 outputs (462 = 22*21)
#define T5  21
#define L0T 859
#define L1T 427
#define L2T 211
#define L3T 103
#define L4T 49
#define SS1 432
#define SS2 216
#define SS3 108
#define SS4 49           // odd -> stage-5 reads conflict-free

__device__ __forceinline__ float gelu_exact(float x) {
    return 0.5f * x * (1.0f + erff(x * 0.7071067811865476f));
}

// c[r] = sum_{2p+q=r, p,q in [0,4)} A[p]*B[q]
__device__ __forceinline__ void composite10(const float* A, const float* Bv, float* c) {
#pragma unroll
    for (int r = 0; r < 10; ++r) {
        float acc = 0.f;
#pragma unroll
        for (int p = 0; p < 4; ++p) {
            int q = r - 2 * p;
            if (q >= 0 && q < 4) acc = fmaf(A[p], Bv[q], acc);
        }
        c[r] = acc;
    }
}

// blocks 0..117: transpose x [B][15000][21] -> xT [B][21][15000]
// blocks 118/119: prep cheCT[b][m][k] + cheLN4[b][{L,N,V0,V511}][k]
__global__ __launch_bounds__(256)
void transpose_prep_kernel(const float* __restrict__ in, float* __restrict__ out,
                           const float* __restrict__ table, const int* __restrict__ chv,
                           const float* __restrict__ mw1, const float* __restrict__ mw2,
                           float* __restrict__ cheCT, float* __restrict__ cheLN4)
{
    const int bx = blockIdx.x;
    if (bx >= 118) {
        const int b = bx - 118;
        const int m = threadIdx.x;
        if (m >= 128) return;
        float W1[4], W2[4], c2[10];
#pragma unroll
        for (int q = 0; q < 4; ++q) { W1[q] = mw1[q]; W2[q] = mw2[q]; }
        composite10(W2, W1, c2);
        for (int k = 0; k < 21; ++k) {
            const float* cb = table + (long)chv[b * 21 + k] * 512;
            float acc = 0.f;
            if (m == 0) {
#pragma unroll
                for (int r = 3; r < 10; ++r) acc = fmaf(c2[r], cb[r - 3], acc);
            } else if (m == 127) {
#pragma unroll
                for (int r = 0; r < 7; ++r) acc = fmaf(c2[r], cb[505 + r], acc);
            } else {
                int j0 = 4 * m - 3;
#pragma unroll
                for (int r = 0; r < 10; ++r) acc = fmaf(c2[r], cb[j0 + r], acc);
            }
            cheCT[b * 2688 + m * 21 + k] = acc;
        }
        if (m < 21) {
            const float* cb = table + (long)chv[b * 21 + m] * 512;
            float l = 0.f, n = 0.f;
#pragma unroll
            for (int r = 0; r < 3; ++r)  l = fmaf(c2[r], cb[509 + r], l);
#pragma unroll
            for (int r = 7; r < 10; ++r) n = fmaf(c2[r], cb[r - 7], n);
            cheLN4[b * 84 + m]      = l;        // L
            cheLN4[b * 84 + 21 + m] = n;        // N
            cheLN4[b * 84 + 42 + m] = cb[0];    // V0
            cheLN4[b * 84 + 63 + m] = cb[511];  // V511
        }
        return;
    }
    // ---- transpose ----
    __shared__ float s[21 * 257];
    const int b   = bx & 1;
    const int t0  = (bx >> 1) * 256;
    const int tid = threadIdx.x;
    const float* src = in + (long)b * 315000L + (long)t0 * 21L;
    const int limit = 315000 - t0 * 21;
#pragma unroll
    for (int j = 0; j < 21; ++j) {
        int f = tid + j * 256;
        if (f < limit) {
            int t = f / 21, c = f - t * 21;
            s[c * 257 + t] = src[f];
        }
    }
    __syncthreads();
    float* dst = out + (long)b * 315000L + t0;
    if (t0 + tid < 15000) {
#pragma unroll
        for (int c = 0; c < 21; ++c)
            dst[c * 15000 + tid] = s[c * 257 + tid];
    }
}

// All 5 depthwise stages for one (b, orig-channel c, time tile) in LDS.
__global__ __launch_bounds__(256, 5)
void conv_stack_kernel(const float* __restrict__ xT,
                       const float* __restrict__ w1, const float* __restrict__ b1,
                       const float* __restrict__ w2, const float* __restrict__ b2,
                       const float* __restrict__ w3, const float* __restrict__ b3,
                       const float* __restrict__ w4, const float* __restrict__ b4,
                       const float* __restrict__ w5, const float* __restrict__ b5,
                       float* __restrict__ embT)
{
    __shared__ __align__(16) float A[3456];   // x(859) -> s2(16x216) -> s4(64x49)
    __shared__ __align__(16) float B[3456];   // s1(8x432) -> s3(32x108)
    const int tile = blockIdx.x;
    const int c    = blockIdx.y;
    const int b    = blockIdx.z;
    const int tid  = threadIdx.x;
    const int lane = tid & 63;
    const int wq   = tid >> 6;
    const int t0   = tile * T5;

    const float* xp = xT + ((long)b * 21 + c) * 15000L + 32 * t0;
    for (int i = tid; i < L0T; i += 256) A[i] = xp[i];
    __syncthreads();

    auto convK7 = [&](const float* SIN, int sstride, bool from_x,
                      float* SOUT, int ostride,
                      const float* wg, const float* bg, int wbase,
                      int nch, int pairs, int Lout, bool b64st) {
        for (int it = 0; it < (nch >> 2); ++it) {
            const int chg = __builtin_amdgcn_readfirstlane((it << 2) + wq);
            const float* wp = wg + (size_t)(wbase + chg) * 7;
            const float W0 = wp[0], Wa = wp[1], Wb = wp[2], Wc = wp[3],
                        Wd = wp[4], We = wp[5], Wf = wp[6];
            const float bb = bg[wbase + chg];
            const float* sin_ch = SIN + (from_x ? 0 : (chg >> 1) * sstride);
            float* sout_ch = SOUT + chg * ostride;
            for (int j = lane; j < pairs; j += 64) {
                const int p = 2 * j;
                const float* s = sin_ch + p * 2;
                const float4 u0 = *(const float4*)(s);
                const float4 u1 = *(const float4*)(s + 4);
                const float4 u2 = *(const float4*)(s + 8);
                float o0 = bb, o1 = bb;
                o0 = fmaf(W0, u0.x, o0); o0 = fmaf(Wa, u0.y, o0); o0 = fmaf(Wb, u0.z, o0);
                o0 = fmaf(Wc, u0.w, o0); o0 = fmaf(Wd, u1.x, o0); o0 = fmaf(We, u1.y, o0);
                o0 = fmaf(Wf, u1.z, o0);
                o1 = fmaf(W0, u0.z, o1); o1 = fmaf(Wa, u0.w, o1); o1 = fmaf(Wb, u1.x, o1);
                o1 = fmaf(Wc, u1.y, o1); o1 = fmaf(Wd, u1.z, o1); o1 = fmaf(We, u1.w, o1);
                o1 = fmaf(Wf, u2.x, o1);
                if (p + 1 < Lout) {
                    if (b64st) *(float2*)(sout_ch + p) = make_float2(o0, o1);
                    else       { sout_ch[p] = o0; sout_ch[p + 1] = o1; }
                } else {
                    sout_ch[p] = o0;
                }
            }
        }
    };

    convK7(A, 0,   true,  B, SS1, w1, b1, 8 * c,  8,  214, L1T, true);
    __syncthreads();
    convK7(B, SS1, false, A, SS2, w2, b2, 16 * c, 16, 106, L2T, true);
    __syncthreads();
    convK7(A, SS2, false, B, SS3, w3, b3, 32 * c, 32, 52,  L3T, true);
    __syncthreads();
    convK7(B, SS3, false, A, SS4, w4, b4, 64 * c, 64, 25,  L4T, false);
    __syncthreads();

    // stage 5 (K=9) -> embT [b][t][2688], coalesced writes
    {
        const int ch5 = tid & 127;
        const int th  = tid >> 7;
        const float* wp = w5 + (size_t)(128 * c + ch5) * 9;
        float V[9];
#pragma unroll
        for (int k = 0; k < 9; ++k) V[k] = wp[k];
        const float bb = b5[128 * c + ch5];
        const float* s4ch = A + (ch5 >> 1) * SS4;
        float* obase = embT + ((long)(b * TR + t0)) * C5 + 128 * c + ch5;
#pragma unroll
        for (int iu = 0; iu < 11; ++iu) {
            const int tl = th + 2 * iu;
            if (tl < T5) {
                const float* sp = s4ch + 2 * tl;
                float acc = bb;
#pragma unroll
                for (int k = 0; k < 9; ++k) acc = fmaf(V[k], sp[k], acc);
                obase[(long)tl * C5] = acc;
            }
        }
    }
}

// Fused einsum+tail-convs. One block per (b,t), 512 threads.
// i = tid&127 (emb row, VGPRs), mq = tid>>7 (m-chunk of 32, wave-uniform).
// g2 in registers G[32]; halos via s_L/s_R; results staged through stride-33
// LDS rows and stored coalesced. NO occupancy request: let VGPRs float
// (~110-130) so G[32] stays in registers instead of spilling to scratch.
__global__ __launch_bounds__(512)
void fused_embed_kernel(const float* __restrict__ embT,   // [B][Tr][2688]
                        const float* __restrict__ cheCT,  // [B][128][21]
                        const float* __restrict__ cheLN4, // [B][4][21]
                        const float* __restrict__ mw1, const float* __restrict__ mb1,
                        const float* __restrict__ mw2, const float* __restrict__ mb2,
                        const float* __restrict__ mw3, const float* __restrict__ mb3,
                        const float* __restrict__ mw4, const float* __restrict__ mb4,
                        float* __restrict__ out)
{
    __shared__ __align__(16) float s_mem[5844];
    float* s_emb = s_mem;           // [0, 2688)
    float* s_L   = s_mem + 2688;    // [2688, 4224)
    float* s_R   = s_mem + 4224;    // [4224, 5760)
    float* s_ln  = s_mem + 5760;    // [5760, 5844)
    float* s_out = s_mem;           // aliases [0, 4224) -- dead s_emb/s_L space

    const int t   = blockIdx.x;
    const int b   = blockIdx.y;
    const int tid = threadIdx.x;
    const int i   = tid & 127;
    const int mq  = __builtin_amdgcn_readfirstlane(tid >> 7);

    // one coalesced burst: emb row -> LDS
    const float* erow = embT + ((long)(b * TR + t)) * C5;
    for (int j = tid; j < 672; j += 512)
        *(float4*)&s_emb[j * 4] = ((const float4*)erow)[j];
    if (tid < 84) s_ln[tid] = cheLN4[b * 84 + tid];

    float W1[4], W2[4], W3[4], W4[4];
#pragma unroll
    for (int q = 0; q < 4; ++q) { W1[q] = mw1[q]; W2[q] = mw2[q]; W3[q] = mw3[q]; W4[q] = mw4[q]; }
    const float B1 = mb1[0], B2 = mb2[0], B3 = mb3[0], B4 = mb4[0];
    const float Bc  = B2 + B1 * (W2[0] + W2[1] + W2[2] + W2[3]);
    float c4[10];
    composite10(W4, W3, c4);
    const float Bc2 = B4 + B3 * (W4[0] + W4[1] + W4[2] + W4[3]);

    __syncthreads();

    // emb row i -> registers (stride 21 coprime 32 banks: 2-way max, free)
    float er[21];
#pragma unroll
    for (int k = 0; k < 21; ++k) er[k] = s_emb[i * 21 + k];

    // ---- phase A: raw z2 for 32 m into G (cheCT via wave-uniform s_loads) ----
    float G[32];
    const float* cp = cheCT + (b * 128 + mq * 32) * 21;
#pragma unroll
    for (int mi4 = 0; mi4 < 8; ++mi4) {
        const float* cc = cp + mi4 * 84;
        float z0 = Bc, z1 = Bc, z2 = Bc, z3 = Bc;
#pragma unroll
        for (int k = 0; k < 21; ++k) {
            const float e = er[k];
            z0 = fmaf(e, cc[k],      z0);
            z1 = fmaf(e, cc[21 + k], z1);
            z2 = fmaf(e, cc[42 + k], z2);
            z3 = fmaf(e, cc[63 + k], z3);
        }
        G[4 * mi4 + 0] = z0; G[4 * mi4 + 1] = z1;
        G[4 * mi4 + 2] = z2; G[4 * mi4 + 3] = z3;
    }

    // ---- boundary-column corrections (wave-uniform mq branches) ----
    if (mq == 0) {            // owns m = 0
        float corr = 0.f;
        if (i == 0) {
            float w0 = 0.f;
#pragma unroll
            for (int k = 0; k < 21; ++k) w0 = fmaf(er[k], s_ln[42 + k], w0);
            corr = -W2[0] * (B1 + W1[3] * w0);
        } else {
#pragma unroll
            for (int k = 0; k < 21; ++k) corr = fmaf(s_emb[(i - 1) * 21 + k], s_ln[k], corr);
        }
        G[0] += corr;
    } else if (mq == 3) {     // owns m = 127
        float corr = 0.f;
        if (i == 127) {
            float wl = 0.f;
#pragma unroll
            for (int k = 0; k < 21; ++k) wl = fmaf(er[k], s_ln[63 + k], wl);
            corr = -W2[3] * (B1 + W1[0] * wl);
        } else {
#pragma unroll
            for (int k = 0; k < 21; ++k) corr = fmaf(s_emb[(i + 1) * 21 + k], s_ln[21 + k], corr);
        }
        G[31] += corr;
    }

#pragma unroll
    for (int j = 0; j < 32; ++j) G[j] = gelu_exact(G[j]);

    // ---- publish halos (lane-consecutive: conflict-free) ----
#pragma unroll
    for (int c = 0; c < 3; ++c) {
        s_L[c * 512 + tid] = G[c];
        s_R[c * 512 + tid] = G[29 + c];
    }
    __syncthreads();

    float Lh[3], Rh[3];
    {
        const int  tl = (mq == 0) ? (383 + i) : (tid - 128);
        const bool lz = (mq == 0) && (i == 0);
        const int  tr = (mq == 3) ? (i + 1) : (tid + 128);
        const bool rz = (mq == 3) && (i == 127);
#pragma unroll
        for (int c = 0; c < 3; ++c) {
            Lh[c] = lz ? 0.f : s_R[c * 512 + tl];
            Rh[c] = rz ? 0.f : s_L[c * 512 + tr];
        }
    }

    // ---- phase B: composite conv3∘conv4 on registers, gelu ----
    float res[8];
#pragma unroll
    for (int s = 0; s < 8; ++s) {
        float z = Bc2;
#pragma unroll
        for (int r = 0; r < 10; ++r) {
            const int j = 4 * s - 3 + r;
            const float g = (j < 0) ? Lh[3 + j] : ((j < 32) ? G[j] : Rh[j - 32]);
            z = fmaf(c4[r], g, z);
        }
        res[s] = z;
    }
    if (mq == 0 && i == 0)   res[0] -= W4[0] * (B3 + W3[3] * G[0]);
    if (mq == 3 && i == 127) res[7] -= W4[3] * (B3 + W3[0] * G[31]);
#pragma unroll
    for (int s = 0; s < 8; ++s) res[s] = gelu_exact(res[s]);

    // ---- stage to LDS (stride-33 rows: conflict-free writes) ----
    __syncthreads();   // all halo reads done; safe to overwrite s_emb/s_L space
    {
        float* so = s_out + 33 * i + 8 * mq;
#pragma unroll
        for (int s = 0; s < 8; ++s) so[s] = res[s];
    }
    __syncthreads();

    // ---- coalesced store: lane-consecutive float4s ----
    float* orow = out + ((long)(b * TR + t)) * OUTROW;
#pragma unroll
    for (int s2 = 0; s2 < 2; ++s2) {
        const int p4 = tid + 512 * s2;              // float4 index, 0..1023
        const float* sp = s_out + 33 * (p4 >> 3) + 4 * (p4 & 7);
        ((float4*)orow)[p4] = make_float4(sp[0], sp[1], sp[2], sp[3]);
    }
}

extern "C" void kernel_launch(void* const* d_in, const int* in_sizes, int n_in,
                              void* d_out, int out_size, void* d_ws, size_t ws_size,
                              hipStream_t stream)
{
    const float* x   = (const float*)d_in[0];
    const int*   chv = (const int*)d_in[1];
    const float* w1  = (const float*)d_in[2];  const float* b1 = (const float*)d_in[3];
    const float* w2  = (const float*)d_in[4];  const float* b2 = (const float*)d_in[5];
    const float* w3  = (const float*)d_in[6];  const float* b3 = (const float*)d_in[7];
    const float* w4  = (const float*)d_in[8];  const float* b4 = (const float*)d_in[9];
    const float* w5  = (const float*)d_in[10]; const float* b5 = (const float*)d_in[11];
    const float* tab = (const float*)d_in[12];
    const float* mw1 = (const float*)d_in[13]; const float* mb1 = (const float*)d_in[14];
    const float* mw2 = (const float*)d_in[15]; const float* mb2 = (const float*)d_in[16];
    const float* mw3 = (const float*)d_in[17]; const float* mb3 = (const float*)d_in[18];
    const float* mw4 = (const float*)d_in[19]; const float* mb4 = (const float*)d_in[20];
    float* outp = (float*)d_out;

    float* ws     = (float*)d_ws;
    float* xT     = ws;                 // 630,000 floats
    float* embT   = ws + 630000;        // 2,483,712 floats (16B aligned)
    float* cheCT  = ws + 3113712;       // 5,376
    float* cheLN4 = ws + 3119088;       // 168

    transpose_prep_kernel<<<120, 256, 0, stream>>>(x, xT, tab, chv, mw1, mw2,
                                                   cheCT, cheLN4);
    {
        dim3 grid(22, 21, NB);   // tile, c, b
        conv_stack_kernel<<<grid, 256, 0, stream>>>(xT, w1, b1, w2, b2, w3, b3,
                                                    w4, b4, w5, b5, embT);
    }
    {
        dim3 grid(TR, NB);  // t, b
        fused_embed_kernel<<<grid, 512, 0, stream>>>(embT, cheCT, cheLN4,
                                                     mw1, mb1, mw2, mb2, mw3, mb3, mw4, mb4,
                                                     outp);
    }
}

// Round 10
// 51.219 us; speedup vs baseline: 1.8367x; 1.8367x over previous
//
#include <hip/hip_runtime.h>
#include <math.h>

// ---------------------------------------------------------------------------
// InputEmbedder. Sizes: B=2, T=15000, CHNLS=21, HIDDEN=128, Tr=462
// R10: TWO dispatches total.
//  1) conv_stack_prep: 5-stage depthwise stack per (b,c,tile) reading x
//     DIRECTLY (stride-21 loads, L2-absorbed; transpose kernel deleted),
//     T5=42; prep (cheCT/cheLN4) folded in as tile index 11.
//  2) fused_embed: R8's proven s_g2-LDS structure, verbatim.
// Rationale: R9 showed ~20-30us of the 60us total is per-dispatch overhead;
// register-G fused structure is codegen-hostile (2x VALU) -- abandoned.
// ---------------------------------------------------------------------------

#define NB 2
#define TR 462
#define C5 2688          // HIDDEN*CHNLS
#define OUTROW 4096      // HIDDEN*32

// conv-stack tiling: 11 tiles of T5=42 stage-5 outputs (462 = 11*42)
#define T5  42
#define L0T 1531
#define L1T 763
#define L2T 379
#define L3T 187
#define L4T 91
#define SS1 768
#define SS2 384
#define SS3 192
#define SS4 93           // odd -> stage-5 reads conflict-free

__device__ __forceinline__ float gelu_exact(float x) {
    return 0.5f * x * (1.0f + erff(x * 0.7071067811865476f));
}

// float4-granularity XOR swizzle for s_g2 (breaks stride-128 bank aliasing)
__device__ __forceinline__ int swz(int a) { return a ^ (((a >> 7) & 7) << 2); }

// c[r] = sum_{2p+q=r, p,q in [0,4)} A[p]*B[q]
__device__ __forceinline__ void composite10(const float* A, const float* Bv, float* c) {
#pragma unroll
    for (int r = 0; r < 10; ++r) {
        float acc = 0.f;
#pragma unroll
        for (int p = 0; p < 4; ++p) {
            int q = r - 2 * p;
            if (q >= 0 && q < 4) acc = fmaf(A[p], Bv[q], acc);
        }
        c[r] = acc;
    }
}

// All 5 depthwise stages for one (b, orig-channel c, time tile) in LDS.
// tile == 11 (c == 0 only): prep cheCT[b][m][k] + cheLN4[b][{L,N,V0,V511}][k].
__global__ __launch_bounds__(256)
void conv_stack_prep_kernel(const float* __restrict__ x,
                            const float* __restrict__ w1, const float* __restrict__ b1,
                            const float* __restrict__ w2, const float* __restrict__ b2,
                            const float* __restrict__ w3, const float* __restrict__ b3,
                            const float* __restrict__ w4, const float* __restrict__ b4,
                            const float* __restrict__ w5, const float* __restrict__ b5,
                            const float* __restrict__ table, const int* __restrict__ chv,
                            const float* __restrict__ mw1, const float* __restrict__ mw2,
                            float* __restrict__ embT,
                            float* __restrict__ cheCT, float* __restrict__ cheLN4)
{
    const int tile = blockIdx.x;
    const int c    = blockIdx.y;
    const int b    = blockIdx.z;
    const int tid  = threadIdx.x;

    if (tile == 11) {
        // ---- prep branch (2 useful blocks) ----
        if (c != 0 || tid >= 128) return;
        const int m = tid;
        float W1[4], W2[4], c2[10];
#pragma unroll
        for (int q = 0; q < 4; ++q) { W1[q] = mw1[q]; W2[q] = mw2[q]; }
        composite10(W2, W1, c2);
        for (int k = 0; k < 21; ++k) {
            const float* cb = table + (long)chv[b * 21 + k] * 512;
            float acc = 0.f;
            if (m == 0) {
#pragma unroll
                for (int r = 3; r < 10; ++r) acc = fmaf(c2[r], cb[r - 3], acc);
            } else if (m == 127) {
#pragma unroll
                for (int r = 0; r < 7; ++r) acc = fmaf(c2[r], cb[505 + r], acc);
            } else {
                int j0 = 4 * m - 3;
#pragma unroll
                for (int r = 0; r < 10; ++r) acc = fmaf(c2[r], cb[j0 + r], acc);
            }
            cheCT[b * 2688 + m * 21 + k] = acc;
        }
        if (m < 21) {
            const float* cb = table + (long)chv[b * 21 + m] * 512;
            float l = 0.f, n = 0.f;
#pragma unroll
            for (int r = 0; r < 3; ++r)  l = fmaf(c2[r], cb[509 + r], l);
#pragma unroll
            for (int r = 7; r < 10; ++r) n = fmaf(c2[r], cb[r - 7], n);
            cheLN4[b * 84 + m]      = l;        // L
            cheLN4[b * 84 + 21 + m] = n;        // N
            cheLN4[b * 84 + 42 + m] = cb[0];    // V0
            cheLN4[b * 84 + 63 + m] = cb[511];  // V511
        }
        return;
    }

    __shared__ __align__(16) float A[6144];   // x(1531) -> s2(16x384) -> s4(64x93)
    __shared__ __align__(16) float B[6144];   // s1(8x768) -> s3(32x192)
    const int lane = tid & 63;
    const int wq   = tid >> 6;
    const int t0   = tile * T5;

    // ---- stage-0 load: x[b][32*t0 + i][c], stride-21 (L2-absorbed) ----
    {
        const float* xp = x + (long)b * 315000L + (long)(32 * t0) * 21L + c;
        for (int i = tid; i < L0T; i += 256) A[i] = xp[(long)i * 21L];
    }
    __syncthreads();

    auto convK7 = [&](const float* SIN, int sstride, bool from_x,
                      float* SOUT, int ostride,
                      const float* wg, const float* bg, int wbase,
                      int nch, int pairs, int Lout, bool b64st) {
        for (int it = 0; it < (nch >> 2); ++it) {
            const int chg = __builtin_amdgcn_readfirstlane((it << 2) + wq);
            const float* wp = wg + (size_t)(wbase + chg) * 7;
            const float W0 = wp[0], Wa = wp[1], Wb = wp[2], Wc = wp[3],
                        Wd = wp[4], We = wp[5], Wf = wp[6];
            const float bb = bg[wbase + chg];
            const float* sin_ch = SIN + (from_x ? 0 : (chg >> 1) * sstride);
            float* sout_ch = SOUT + chg * ostride;
            for (int j = lane; j < pairs; j += 64) {
                const int p = 2 * j;
                const float* s = sin_ch + p * 2;
                const float4 u0 = *(const float4*)(s);
                const float4 u1 = *(const float4*)(s + 4);
                const float4 u2 = *(const float4*)(s + 8);
                float o0 = bb, o1 = bb;
                o0 = fmaf(W0, u0.x, o0); o0 = fmaf(Wa, u0.y, o0); o0 = fmaf(Wb, u0.z, o0);
                o0 = fmaf(Wc, u0.w, o0); o0 = fmaf(Wd, u1.x, o0); o0 = fmaf(We, u1.y, o0);
                o0 = fmaf(Wf, u1.z, o0);
                o1 = fmaf(W0, u0.z, o1); o1 = fmaf(Wa, u0.w, o1); o1 = fmaf(Wb, u1.x, o1);
                o1 = fmaf(Wc, u1.y, o1); o1 = fmaf(Wd, u1.z, o1); o1 = fmaf(We, u1.w, o1);
                o1 = fmaf(Wf, u2.x, o1);
                if (p + 1 < Lout) {
                    if (b64st) *(float2*)(sout_ch + p) = make_float2(o0, o1);
                    else       { sout_ch[p] = o0; sout_ch[p + 1] = o1; }
                } else {
                    sout_ch[p] = o0;
                }
            }
        }
    };

    convK7(A, 0,   true,  B, SS1, w1, b1, 8 * c,  8,  382, L1T, true);
    __syncthreads();
    convK7(B, SS1, false, A, SS2, w2, b2, 16 * c, 16, 190, L2T, true);
    __syncthreads();
    convK7(A, SS2, false, B, SS3, w3, b3, 32 * c, 32, 94,  L3T, true);
    __syncthreads();
    convK7(B, SS3, false, A, SS4, w4, b4, 64 * c, 64, 46,  L4T, false);
    __syncthreads();

    // stage 5 (K=9) -> embT [b][t][2688], coalesced writes
    {
        const int ch5 = tid & 127;
        const int th  = tid >> 7;
        const float* wp = w5 + (size_t)(128 * c + ch5) * 9;
        float V[9];
#pragma unroll
        for (int k = 0; k < 9; ++k) V[k] = wp[k];
        const float bb = b5[128 * c + ch5];
        const float* s4ch = A + (ch5 >> 1) * SS4;
        float* obase = embT + ((long)(b * TR + t0)) * C5 + 128 * c + ch5;
#pragma unroll
        for (int iu = 0; iu < 21; ++iu) {
            const int tl = th + 2 * iu;
            const float* sp = s4ch + 2 * tl;
            float acc = bb;
#pragma unroll
            for (int k = 0; k < 9; ++k) acc = fmaf(V[k], sp[k], acc);
            obase[(long)tl * C5] = acc;
        }
    }
}

// Fused einsum+tail-convs, one block per (b,t), 512 threads. (R8 verbatim.)
// thread: i = tid&127 (emb row in VGPRs), mq = tid>>7 (m-chunk of 32).
// Boundary corrections folded into phase A (wave-uniform mq branches).
__global__ __launch_bounds__(512, 4)
void fused_embed_kernel(const float* __restrict__ embT,   // [B][Tr][2688]
                        const float* __restrict__ cheCT,  // [B][128][21]
                        const float* __restrict__ cheLN4, // [B][4][21]
                        const float* __restrict__ mw1, const float* __restrict__ mb1,
                        const float* __restrict__ mw2, const float* __restrict__ mb2,
                        const float* __restrict__ mw3, const float* __restrict__ mb3,
                        const float* __restrict__ mw4, const float* __restrict__ mb4,
                        float* __restrict__ out)
{
    __shared__ float s_g2[16400];   // slot = swz(4 + u), u in [0,16384); pads zero
    __shared__ float s_emb[2688];
    __shared__ float s_ln[84];

    const int t   = blockIdx.x;
    const int b   = blockIdx.y;
    const int tid = threadIdx.x;
    const int i   = tid & 127;
    const int mq  = __builtin_amdgcn_readfirstlane(tid >> 7);

    // one coalesced burst: emb row -> LDS
    const float* erow = embT + ((long)(b * TR + t)) * C5;
    for (int j = tid; j < 672; j += 512)
        *(float4*)&s_emb[j * 4] = ((const float4*)erow)[j];
    if (tid < 84) s_ln[tid] = cheLN4[b * 84 + tid];
    if (tid < 4)       s_g2[tid] = 0.f;
    else if (tid < 20) s_g2[16380 + tid] = 0.f;

    float W1[4], W2[4], W3[4], W4[4];
#pragma unroll
    for (int q = 0; q < 4; ++q) { W1[q] = mw1[q]; W2[q] = mw2[q]; W3[q] = mw3[q]; W4[q] = mw4[q]; }
    const float B1 = mb1[0], B2 = mb2[0], B3 = mb3[0], B4 = mb4[0];
    const float Bc = B2 + B1 * (W2[0] + W2[1] + W2[2] + W2[3]);

    __syncthreads();

    // emb row i -> registers (stride 21 coprime 32 banks: conflict-free)
    float er[21];
#pragma unroll
    for (int k = 0; k < 21; ++k) er[k] = s_emb[i * 21 + k];

    // ---- phase A: z2/g2 for 32 m per thread, 4 chains per float4;
    //      m=0 / m=127 corrections folded in (wave-uniform mq) ----
    const float* cp = cheCT + (b * 128 + mq * 32) * 21;   // uniform -> s_load
#pragma unroll
    for (int mi4 = 0; mi4 < 8; ++mi4) {
        const int m0 = mq * 32 + mi4 * 4;
        const float* cc = cp + mi4 * 84;
        float z0 = Bc, z1 = Bc, z2 = Bc, z3 = Bc;
#pragma unroll
        for (int k = 0; k < 21; ++k) {
            const float e = er[k];
            z0 = fmaf(e, cc[k],      z0);
            z1 = fmaf(e, cc[21 + k], z1);
            z2 = fmaf(e, cc[42 + k], z2);
            z3 = fmaf(e, cc[63 + k], z3);
        }
        if (mi4 == 0 && mq == 0) {           // z0 is m = 0
            float corr = 0.f;
            if (i == 0) {
                float w0 = 0.f;
#pragma unroll
                for (int k = 0; k < 21; ++k) w0 = fmaf(er[k], s_ln[42 + k], w0);
                corr = -W2[0] * (B1 + W1[3] * w0);
            } else {
#pragma unroll
                for (int k = 0; k < 21; ++k) corr = fmaf(s_emb[(i - 1) * 21 + k], s_ln[k], corr);
            }
            z0 += corr;
        }
        if (mi4 == 7 && mq == 3) {           // z3 is m = 127
            float corr = 0.f;
            if (i == 127) {
                float wl = 0.f;
#pragma unroll
                for (int k = 0; k < 21; ++k) wl = fmaf(er[k], s_ln[63 + k], wl);
                corr = -W2[3] * (B1 + W1[0] * wl);
            } else {
#pragma unroll
                for (int k = 0; k < 21; ++k) corr = fmaf(s_emb[(i + 1) * 21 + k], s_ln[21 + k], corr);
            }
            z3 += corr;
        }
        float4 q;
        q.x = gelu_exact(z0);
        q.y = gelu_exact(z1);
        q.z = gelu_exact(z2);
        q.w = gelu_exact(z3);
        *(float4*)&s_g2[swz(4 + i * 128 + m0)] = q;
    }
    __syncthreads();

    // ---- phase B: composite conv3∘conv4, gelu, coalesced store ----
    float c4[10];
    composite10(W4, W3, c4);
    const float Bc2 = B4 + B3 * (W4[0] + W4[1] + W4[2] + W4[3]);
    float* orow = out + ((long)(b * TR + t)) * OUTROW;
#pragma unroll
    for (int s = 0; s < 8; ++s) {
        const int p  = tid + 512 * s;
        const int a0 = 4 * p;
        const float4 v0 = *(const float4*)&s_g2[swz(a0)];
        const float4 v1 = *(const float4*)&s_g2[swz(a0 + 4)];
        const float4 v2 = *(const float4*)&s_g2[swz(a0 + 8)];
        const float buf[12] = { v0.x, v0.y, v0.z, v0.w,
                                v1.x, v1.y, v1.z, v1.w,
                                v2.x, v2.y, v2.z, v2.w };
        float z = Bc2;
#pragma unroll
        for (int r = 0; r < 10; ++r) z = fmaf(c4[r], buf[r + 1], z);
        if (p == 0)    z -= W4[0] * (B3 + W3[3] * s_g2[swz(4)]);
        if (p == 4095) z -= W4[3] * (B3 + W3[0] * s_g2[swz(16387)]);
        orow[p] = gelu_exact(z);
    }
}

extern "C" void kernel_launch(void* const* d_in, const int* in_sizes, int n_in,
                              void* d_out, int out_size, void* d_ws, size_t ws_size,
                              hipStream_t stream)
{
    const float* x   = (const float*)d_in[0];
    const int*   chv = (const int*)d_in[1];
    const float* w1  = (const float*)d_in[2];  const float* b1 = (const float*)d_in[3];
    const float* w2  = (const float*)d_in[4];  const float* b2 = (const float*)d_in[5];
    const float* w3  = (const float*)d_in[6];  const float* b3 = (const float*)d_in[7];
    const float* w4  = (const float*)d_in[8];  const float* b4 = (const float*)d_in[9];
    const float* w5  = (const float*)d_in[10]; const float* b5 = (const float*)d_in[11];
    const float* tab = (const float*)d_in[12];
    const float* mw1 = (const float*)d_in[13]; const float* mb1 = (const float*)d_in[14];
    const float* mw2 = (const float*)d_in[15]; const float* mb2 = (const float*)d_in[16];
    const float* mw3 = (const float*)d_in[17]; const float* mb3 = (const float*)d_in[18];
    const float* mw4 = (const float*)d_in[19]; const float* mb4 = (const float*)d_in[20];
    float* outp = (float*)d_out;

    float* ws     = (float*)d_ws;
    float* embT   = ws;                 // 2,483,712 floats (16B aligned)
    float* cheCT  = ws + 2483712;       // 5,376
    float* cheLN4 = ws + 2489088;       // 168

    {
        dim3 grid(12, 21, NB);   // tile (11 = prep), c, b
        conv_stack_prep_kernel<<<grid, 256, 0, stream>>>(x, w1, b1, w2, b2, w3, b3,
                                                         w4, b4, w5, b5,
                                                         tab, chv, mw1, mw2,
                                                         embT, cheCT, cheLN4);
    }
    {
        dim3 grid(TR, NB);  // t, b
        fused_embed_kernel<<<grid, 512, 0, stream>>>(embT, cheCT, cheLN4,
                                                     mw1, mb1, mw2, mb2, mw3, mb3, mw4, mb4,
                                                     outp);
    }
}

// Round 11
// 49.355 us; speedup vs baseline: 1.9060x; 1.0378x over previous
//
#include <hip/hip_runtime.h>
#include <math.h>

// ---------------------------------------------------------------------------
// InputEmbedder. Sizes: B=2, T=15000, CHNLS=21, HIDDEN=128, Tr=462
// R11: R10 structure, wider blocks for occupancy (LDS is the binder, so pack
// more waves into the same LDS): fused 512->1024 thr (2 blk/CU -> 32 waves/CU
// if VGPR<=64), conv 256->512 thr. No numerics/structure change.
// ---------------------------------------------------------------------------

#define NB 2
#define TR 462
#define C5 2688          // HIDDEN*CHNLS
#define OUTROW 4096      // HIDDEN*32

// conv-stack tiling: 11 tiles of T5=42 stage-5 outputs (462 = 11*42)
#define T5  42
#define L0T 1531
#define L1T 763
#define L2T 379
#define L3T 187
#define L4T 91
#define SS1 768
#define SS2 384
#define SS3 192
#define SS4 93           // odd -> stage-5 reads conflict-free

__device__ __forceinline__ float gelu_exact(float x) {
    return 0.5f * x * (1.0f + erff(x * 0.7071067811865476f));
}

// float4-granularity XOR swizzle for s_g2 (breaks stride-128 bank aliasing)
__device__ __forceinline__ int swz(int a) { return a ^ (((a >> 7) & 7) << 2); }

// c[r] = sum_{2p+q=r, p,q in [0,4)} A[p]*B[q]
__device__ __forceinline__ void composite10(const float* A, const float* Bv, float* c) {
#pragma unroll
    for (int r = 0; r < 10; ++r) {
        float acc = 0.f;
#pragma unroll
        for (int p = 0; p < 4; ++p) {
            int q = r - 2 * p;
            if (q >= 0 && q < 4) acc = fmaf(A[p], Bv[q], acc);
        }
        c[r] = acc;
    }
}

// All 5 depthwise stages for one (b, orig-channel c, time tile) in LDS.
// 512 threads = 8 waves; wave wq handles channel-group (it*8 + wq).
// tile == 11 (c == 0 only): prep cheCT[b][m][k] + cheLN4[b][{L,N,V0,V511}][k].
__global__ __launch_bounds__(512)
void conv_stack_prep_kernel(const float* __restrict__ x,
                            const float* __restrict__ w1, const float* __restrict__ b1,
                            const float* __restrict__ w2, const float* __restrict__ b2,
                            const float* __restrict__ w3, const float* __restrict__ b3,
                            const float* __restrict__ w4, const float* __restrict__ b4,
                            const float* __restrict__ w5, const float* __restrict__ b5,
                            const float* __restrict__ table, const int* __restrict__ chv,
                            const float* __restrict__ mw1, const float* __restrict__ mw2,
                            float* __restrict__ embT,
                            float* __restrict__ cheCT, float* __restrict__ cheLN4)
{
    const int tile = blockIdx.x;
    const int c    = blockIdx.y;
    const int b    = blockIdx.z;
    const int tid  = threadIdx.x;

    if (tile == 11) {
        // ---- prep branch (2 useful blocks) ----
        if (c != 0 || tid >= 128) return;
        const int m = tid;
        float W1[4], W2[4], c2[10];
#pragma unroll
        for (int q = 0; q < 4; ++q) { W1[q] = mw1[q]; W2[q] = mw2[q]; }
        composite10(W2, W1, c2);
        for (int k = 0; k < 21; ++k) {
            const float* cb = table + (long)chv[b * 21 + k] * 512;
            float acc = 0.f;
            if (m == 0) {
#pragma unroll
                for (int r = 3; r < 10; ++r) acc = fmaf(c2[r], cb[r - 3], acc);
            } else if (m == 127) {
#pragma unroll
                for (int r = 0; r < 7; ++r) acc = fmaf(c2[r], cb[505 + r], acc);
            } else {
                int j0 = 4 * m - 3;
#pragma unroll
                for (int r = 0; r < 10; ++r) acc = fmaf(c2[r], cb[j0 + r], acc);
            }
            cheCT[b * 2688 + m * 21 + k] = acc;
        }
        if (m < 21) {
            const float* cb = table + (long)chv[b * 21 + m] * 512;
            float l = 0.f, n = 0.f;
#pragma unroll
            for (int r = 0; r < 3; ++r)  l = fmaf(c2[r], cb[509 + r], l);
#pragma unroll
            for (int r = 7; r < 10; ++r) n = fmaf(c2[r], cb[r - 7], n);
            cheLN4[b * 84 + m]      = l;        // L
            cheLN4[b * 84 + 21 + m] = n;        // N
            cheLN4[b * 84 + 42 + m] = cb[0];    // V0
            cheLN4[b * 84 + 63 + m] = cb[511];  // V511
        }
        return;
    }

    __shared__ __align__(16) float A[6144];   // x(1531) -> s2(16x384) -> s4(64x93)
    __shared__ __align__(16) float B[6144];   // s1(8x768) -> s3(32x192)
    const int lane = tid & 63;
    const int wq   = tid >> 6;        // 0..7
    const int t0   = tile * T5;

    // ---- stage-0 load: x[b][32*t0 + i][c], stride-21 (L2-absorbed) ----
    {
        const float* xp = x + (long)b * 315000L + (long)(32 * t0) * 21L + c;
        for (int i = tid; i < L0T; i += 512) A[i] = xp[(long)i * 21L];
    }
    __syncthreads();

    auto convK7 = [&](const float* SIN, int sstride, bool from_x,
                      float* SOUT, int ostride,
                      const float* wg, const float* bg, int wbase,
                      int nch, int pairs, int Lout, bool b64st) {
        for (int it = 0; it < (nch >> 3); ++it) {
            const int chg = __builtin_amdgcn_readfirstlane((it << 3) + wq);
            const float* wp = wg + (size_t)(wbase + chg) * 7;
            const float W0 = wp[0], Wa = wp[1], Wb = wp[2], Wc = wp[3],
                        Wd = wp[4], We = wp[5], Wf = wp[6];
            const float bb = bg[wbase + chg];
            const float* sin_ch = SIN + (from_x ? 0 : (chg >> 1) * sstride);
            float* sout_ch = SOUT + chg * ostride;
            for (int j = lane; j < pairs; j += 64) {
                const int p = 2 * j;
                const float* s = sin_ch + p * 2;
                const float4 u0 = *(const float4*)(s);
                const float4 u1 = *(const float4*)(s + 4);
                const float4 u2 = *(const float4*)(s + 8);
                float o0 = bb, o1 = bb;
                o0 = fmaf(W0, u0.x, o0); o0 = fmaf(Wa, u0.y, o0); o0 = fmaf(Wb, u0.z, o0);
                o0 = fmaf(Wc, u0.w, o0); o0 = fmaf(Wd, u1.x, o0); o0 = fmaf(We, u1.y, o0);
                o0 = fmaf(Wf, u1.z, o0);
                o1 = fmaf(W0, u0.z, o1); o1 = fmaf(Wa, u0.w, o1); o1 = fmaf(Wb, u1.x, o1);
                o1 = fmaf(Wc, u1.y, o1); o1 = fmaf(Wd, u1.z, o1); o1 = fmaf(We, u1.w, o1);
                o1 = fmaf(Wf, u2.x, o1);
                if (p + 1 < Lout) {
                    if (b64st) *(float2*)(sout_ch + p) = make_float2(o0, o1);
                    else       { sout_ch[p] = o0; sout_ch[p + 1] = o1; }
                } else {
                    sout_ch[p] = o0;
                }
            }
        }
    };

    convK7(A, 0,   true,  B, SS1, w1, b1, 8 * c,  8,  382, L1T, true);
    __syncthreads();
    convK7(B, SS1, false, A, SS2, w2, b2, 16 * c, 16, 190, L2T, true);
    __syncthreads();
    convK7(A, SS2, false, B, SS3, w3, b3, 32 * c, 32, 94,  L3T, true);
    __syncthreads();
    convK7(B, SS3, false, A, SS4, w4, b4, 64 * c, 64, 46,  L4T, false);
    __syncthreads();

    // stage 5 (K=9) -> embT [b][t][2688], coalesced writes
    {
        const int ch5 = tid & 127;
        const int th  = tid >> 7;          // 0..3
        const float* wp = w5 + (size_t)(128 * c + ch5) * 9;
        float V[9];
#pragma unroll
        for (int k = 0; k < 9; ++k) V[k] = wp[k];
        const float bb = b5[128 * c + ch5];
        const float* s4ch = A + (ch5 >> 1) * SS4;
        float* obase = embT + ((long)(b * TR + t0)) * C5 + 128 * c + ch5;
#pragma unroll
        for (int iu = 0; iu < 11; ++iu) {
            const int tl = th + 4 * iu;
            if (tl < T5) {
                const float* sp = s4ch + 2 * tl;
                float acc = bb;
#pragma unroll
                for (int k = 0; k < 9; ++k) acc = fmaf(V[k], sp[k], acc);
                obase[(long)tl * C5] = acc;
            }
        }
    }
}

// Fused einsum+tail-convs, one block per (b,t), 1024 threads (16 waves).
// thread: i = tid&127 (emb row in VGPRs), mq = tid>>7 (m-chunk of 16).
// Boundary corrections folded into phase A (wave-uniform mq branches).
__global__ __launch_bounds__(1024)
void fused_embed_kernel(const float* __restrict__ embT,   // [B][Tr][2688]
                        const float* __restrict__ cheCT,  // [B][128][21]
                        const float* __restrict__ cheLN4, // [B][4][21]
                        const float* __restrict__ mw1, const float* __restrict__ mb1,
                        const float* __restrict__ mw2, const float* __restrict__ mb2,
                        const float* __restrict__ mw3, const float* __restrict__ mb3,
                        const float* __restrict__ mw4, const float* __restrict__ mb4,
                        float* __restrict__ out)
{
    __shared__ float s_g2[16400];   // slot = swz(4 + u), u in [0,16384); pads zero
    __shared__ float s_emb[2688];
    __shared__ float s_ln[84];

    const int t   = blockIdx.x;
    const int b   = blockIdx.y;
    const int tid = threadIdx.x;
    const int i   = tid & 127;
    const int mq  = __builtin_amdgcn_readfirstlane(tid >> 7);   // 0..7

    // one coalesced burst: emb row -> LDS
    const float* erow = embT + ((long)(b * TR + t)) * C5;
    if (tid < 672) *(float4*)&s_emb[tid * 4] = ((const float4*)erow)[tid];
    if (tid >= 672 && tid < 756) s_ln[tid - 672] = cheLN4[b * 84 + (tid - 672)];
    if (tid >= 768 && tid < 772)       s_g2[tid - 768] = 0.f;
    else if (tid >= 772 && tid < 788)  s_g2[16380 + (tid - 772) + 4] = 0.f;

    float W1[4], W2[4], W3[4], W4[4];
#pragma unroll
    for (int q = 0; q < 4; ++q) { W1[q] = mw1[q]; W2[q] = mw2[q]; W3[q] = mw3[q]; W4[q] = mw4[q]; }
    const float B1 = mb1[0], B2 = mb2[0], B3 = mb3[0], B4 = mb4[0];
    const float Bc = B2 + B1 * (W2[0] + W2[1] + W2[2] + W2[3]);

    __syncthreads();

    // emb row i -> registers (stride 21 coprime 32 banks: conflict-free)
    float er[21];
#pragma unroll
    for (int k = 0; k < 21; ++k) er[k] = s_emb[i * 21 + k];

    // ---- phase A: z2/g2 for 16 m per thread, 4 chains per float4;
    //      m=0 / m=127 corrections folded in (wave-uniform mq) ----
    const float* cp = cheCT + (b * 128 + mq * 16) * 21;   // uniform -> s_load
#pragma unroll
    for (int mi4 = 0; mi4 < 4; ++mi4) {
        const int m0 = mq * 16 + mi4 * 4;
        const float* cc = cp + mi4 * 84;
        float z0 = Bc, z1 = Bc, z2 = Bc, z3 = Bc;
#pragma unroll
        for (int k = 0; k < 21; ++k) {
            const float e = er[k];
            z0 = fmaf(e, cc[k],      z0);
            z1 = fmaf(e, cc[21 + k], z1);
            z2 = fmaf(e, cc[42 + k], z2);
            z3 = fmaf(e, cc[63 + k], z3);
        }
        if (mi4 == 0 && mq == 0) {           // z0 is m = 0
            float corr = 0.f;
            if (i == 0) {
                float w0 = 0.f;
#pragma unroll
                for (int k = 0; k < 21; ++k) w0 = fmaf(er[k], s_ln[42 + k], w0);
                corr = -W2[0] * (B1 + W1[3] * w0);
            } else {
#pragma unroll
                for (int k = 0; k < 21; ++k) corr = fmaf(s_emb[(i - 1) * 21 + k], s_ln[k], corr);
            }
            z0 += corr;
        }
        if (mi4 == 3 && mq == 7) {           // z3 is m = 127
            float corr = 0.f;
            if (i == 127) {
                float wl = 0.f;
#pragma unroll
                for (int k = 0; k < 21; ++k) wl = fmaf(er[k], s_ln[63 + k], wl);
                corr = -W2[3] * (B1 + W1[0] * wl);
            } else {
#pragma unroll
                for (int k = 0; k < 21; ++k) corr = fmaf(s_emb[(i + 1) * 21 + k], s_ln[21 + k], corr);
            }
            z3 += corr;
        }
        float4 q;
        q.x = gelu_exact(z0);
        q.y = gelu_exact(z1);
        q.z = gelu_exact(z2);
        q.w = gelu_exact(z3);
        *(float4*)&s_g2[swz(4 + i * 128 + m0)] = q;
    }
    __syncthreads();

    // ---- phase B: composite conv3∘conv4, gelu, coalesced store ----
    float c4[10];
    composite10(W4, W3, c4);
    const float Bc2 = B4 + B3 * (W4[0] + W4[1] + W4[2] + W4[3]);
    float* orow = out + ((long)(b * TR + t)) * OUTROW;
#pragma unroll
    for (int s = 0; s < 4; ++s) {
        const int p  = tid + 1024 * s;
        const int a0 = 4 * p;
        const float4 v0 = *(const float4*)&s_g2[swz(a0)];
        const float4 v1 = *(const float4*)&s_g2[swz(a0 + 4)];
        const float4 v2 = *(const float4*)&s_g2[swz(a0 + 8)];
        const float buf[12] = { v0.x, v0.y, v0.z, v0.w,
                                v1.x, v1.y, v1.z, v1.w,
                                v2.x, v2.y, v2.z, v2.w };
        float z = Bc2;
#pragma unroll
        for (int r = 0; r < 10; ++r) z = fmaf(c4[r], buf[r + 1], z);
        if (p == 0)    z -= W4[0] * (B3 + W3[3] * s_g2[swz(4)]);
        if (p == 4095) z -= W4[3] * (B3 + W3[0] * s_g2[swz(16387)]);
        orow[p] = gelu_exact(z);
    }
}

extern "C" void kernel_launch(void* const* d_in, const int* in_sizes, int n_in,
                              void* d_out, int out_size, void* d_ws, size_t ws_size,
                              hipStream_t stream)
{
    const float* x   = (const float*)d_in[0];
    const int*   chv = (const int*)d_in[1];
    const float* w1  = (const float*)d_in[2];  const float* b1 = (const float*)d_in[3];
    const float* w2  = (const float*)d_in[4];  const float* b2 = (const float*)d_in[5];
    const float* w3  = (const float*)d_in[6];  const float* b3 = (const float*)d_in[7];
    const float* w4  = (const float*)d_in[8];  const float* b4 = (const float*)d_in[9];
    const float* w5  = (const float*)d_in[10]; const float* b5 = (const float*)d_in[11];
    const float* tab = (const float*)d_in[12];
    const float* mw1 = (const float*)d_in[13]; const float* mb1 = (const float*)d_in[14];
    const float* mw2 = (const float*)d_in[15]; const float* mb2 = (const float*)d_in[16];
    const float* mw3 = (const float*)d_in[17]; const float* mb3 = (const float*)d_in[18];
    const float* mw4 = (const float*)d_in[19]; const float* mb4 = (const float*)d_in[20];
    float* outp = (float*)d_out;

    float* ws     = (float*)d_ws;
    float* embT   = ws;                 // 2,483,712 floats (16B aligned)
    float* cheCT  = ws + 2483712;       // 5,376
    float* cheLN4 = ws + 2489088;       // 168

    {
        dim3 grid(12, 21, NB);   // tile (11 = prep), c, b
        conv_stack_prep_kernel<<<grid, 512, 0, stream>>>(x, w1, b1, w2, b2, w3, b3,
                                                         w4, b4, w5, b5,
                                                         tab, chv, mw1, mw2,
                                                         embT, cheCT, cheLN4);
    }
    {
        dim3 grid(TR, NB);  // t, b
        fused_embed_kernel<<<grid, 1024, 0, stream>>>(embT, cheCT, cheLN4,
                                                      mw1, mb1, mw2, mb2, mw3, mb3, mw4, mb4,
                                                      outp);
    }
}